// Round 3
// baseline (13388.997 us; speedup 1.0000x reference)
//
#include <hip/hip_runtime.h>

#define TT 336
#define BB 256
#define DD 128
#define HH 1024
#define TD 43008     // T*D
#define BBHH 262144  // B*H elements

typedef __attribute__((ext_vector_type(8))) short short8;
typedef __attribute__((ext_vector_type(8))) unsigned short ushort8;
typedef __attribute__((ext_vector_type(4))) float floatx4;

// ---- workspace layout (bytes) ----
#define OFF_CNT 0u          // 4 barrier counters, 256 B apart
#define OFF_B1P 4096u       // 4096 f32
#define OFF_B2P 20480u
#define OFF_H1  65536u      // 2 bufs x 512 KB bf16 (swizzled)
#define OFF_H2  1114112u    // 2 bufs x 512 KB
#define OFF_X   2162688u    // 256*336*128 bf16 swizzled = 22020096
#define OFF_W1T 24182784u   // 4096*1152 bf16 = 9437184
#define OFF_W2T 33619968u   // 4096*2048 bf16 = 16777216
// end = 50397184

static __device__ __forceinline__ unsigned short f2bf(float f) {
  unsigned int x = __float_as_uint(f);
  x += 0x7fffu + ((x >> 16) & 1u);   // RNE
  return (unsigned short)(x >> 16);
}
static __device__ __forceinline__ float bf2f(unsigned short u) {
  return __uint_as_float(((unsigned int)u) << 16);
}
static __device__ __forceinline__ float sigm(float x) {
  return 1.f / (1.f + __expf(-x));
}
static __device__ __forceinline__ float tanh_fast(float x) {
  float ax = fabsf(x);
  float e = __expf(-2.f * ax);
  float t = (1.f - e) / (1.f + e);
  return x < 0.f ? -t : t;
}

#define GLOAD_LDS16(gsrc, ldst)                                              \
  __builtin_amdgcn_global_load_lds(                                          \
      (const __attribute__((address_space(1))) void*)(gsrc),                 \
      (__attribute__((address_space(3))) void*)(ldst), 16, 0, 0)

// -------- init: zero counters + h bufs (0..2162688) + d_out --------------
__global__ __launch_bounds__(256) void init_zero(float* out, uint4* span, long n16) {
  long i = (long)blockIdx.x * 256 + threadIdx.x;
  if (i < n16) span[i] = make_uint4(0u, 0u, 0u, 0u);
  if (i == 0) out[0] = 0.f;
}

// ------- features fp32 -> bf16, quad-swizzled by batch row ----------------
__global__ __launch_bounds__(256) void feat2bf(const float* __restrict__ in,
                                               unsigned short* __restrict__ out, long nq) {
  long Q = (long)blockIdx.x * 256 + threadIdx.x;
  if (Q >= nq) return;
  int b = (int)(Q / 5376);
  long outQ = (Q & ~7L) | ((Q ^ (long)b) & 7);
  const floatx4* pp = (const floatx4*)(in + Q * 8);
  floatx4 a = pp[0], c = pp[1];
  ushort8 v;
  #pragma unroll
  for (int q = 0; q < 4; ++q) { v[q] = f2bf(a[q]); v[4 + q] = f2bf(c[q]); }
  *(ushort8*)(out + outQ * 8) = v;
}

// ---- transpose W (K x 4096 f32) -> WT' (4096 x K bf16) -------------------
// gate-interleaved rows: n' = (n&1023)*4 + (n>>10); quad-XOR swizzle keyed n'
__global__ __launch_bounds__(256) void transpose_swz(const float* __restrict__ W,
                                                     unsigned short* __restrict__ out, int K) {
  __shared__ unsigned short tile[64 * 65];
  int tid = threadIdx.x;
  int ktiles = K >> 6;
  int kt = blockIdx.x % ktiles;
  int nt = blockIdx.x / ktiles;
  #pragma unroll
  for (int i = 0; i < 16; ++i) {
    int lin = i * 256 + tid;
    int lk = lin >> 6, nn = lin & 63;
    tile[lk * 65 + nn] = f2bf(W[(size_t)(kt * 64 + lk) * 4096 + nt * 64 + nn]);
  }
  __syncthreads();
  #pragma unroll
  for (int it = 0; it < 2; ++it) {
    int idx = it * 256 + tid;
    int nl = idx >> 3, ql = idx & 7;
    int norig = nt * 64 + nl;
    int np = ((norig & 1023) << 2) | (norig >> 10);
    ushort8 v;
    #pragma unroll
    for (int j = 0; j < 8; ++j) v[j] = tile[(ql * 8 + j) * 65 + nl];
    size_t off = (size_t)np * K + (size_t)((kt * 8 + (ql ^ (np & 7))) << 3);
    *(ushort8*)(out + off) = v;
  }
}

// ---- permute biases: bp[u*4+g] = b[g*1024+u] -----------------------------
__global__ __launch_bounds__(256) void bias_perm(const float* __restrict__ b1,
                                                 const float* __restrict__ b2,
                                                 float* __restrict__ b1p,
                                                 float* __restrict__ b2p) {
  int idx = blockIdx.x * 256 + threadIdx.x;
  const float* src = (idx < 4096) ? b1 : b2;
  float* dst = (idx < 4096) ? b1p : b2p;
  int n = idx & 4095;
  dst[n] = src[(n & 3) * 1024 + (n >> 2)];
}

// ---------------- persistent fused LSTM ----------------
// 256 blocks x 256 thr, 1/CU. layer=bid>>7; tile 64 rows x 128 WT'-rows.
// 4 independent barrier groups (one per mtile: 32 ntiles x 2 layers = 64 blocks).
// c-state in registers; B (and layer0's x-chunk of A) prefetched across barrier.
__global__ __launch_bounds__(256) void lstm_persist(
    const unsigned short* __restrict__ Xbf,
    unsigned short* __restrict__ h1bufs, unsigned short* __restrict__ h2bufs,
    const unsigned short* __restrict__ WT1, const unsigned short* __restrict__ WT2,
    const float* __restrict__ b1p, const float* __restrict__ b2p,
    unsigned int* __restrict__ cnts) {
  __shared__ __align__(16) unsigned short Abuf[2 * 64 * 64];   // 16 KB
  __shared__ __align__(16) unsigned short Bbuf[2 * 128 * 64];  // 32 KB
  __shared__ __align__(16) float zt[64 * 132];                 // 33 KB

  int bid = blockIdx.x;
  int layer = bid >> 7;
  int lid = bid & 127;
  // same (bid & 7) => same XCD under round-robin: co-locate one n-tile's 4 m-blocks
  int ntile = (lid & 7) | (((lid >> 5) & 3) << 3);
  int mtile = (lid >> 3) & 3;
  int m0 = mtile * 64;
  int n0 = ntile * 128;
  int u0 = ntile * 32;

  const unsigned short* Bw = layer ? WT2 : WT1;
  const int K = layer ? 2048 : 1152;
  const int niter = K >> 6;

  int tid = threadIdx.x;
  int w = tid >> 6, lane = tid & 63;
  unsigned int* cnt = cnts + mtile * 64;   // 256 B apart

  auto stageB = [&](int buf, int k0) {
    unsigned short* base = Bbuf + buf * (128 * 64);
    #pragma unroll
    for (int c = 0; c < 4; ++c) {
      int nl = w * 32 + c * 8;
      const unsigned short* src =
          Bw + (size_t)(n0 + nl + (lane >> 3)) * K + k0 + (lane & 7) * 8;
      GLOAD_LDS16(src, base + nl * 64);
    }
  };
  auto stageA = [&](int buf, int k0, int p) {
    const unsigned short* hp1 = h1bufs + (size_t)(p & 1) * BBHH;
    const unsigned short* hp2 = h2bufs + (size_t)(p & 1) * BBHH;
    unsigned short* base = Abuf + buf * (64 * 64);
    #pragma unroll
    for (int c = 0; c < 2; ++c) {
      int ml = w * 16 + c * 8;
      int row = m0 + ml + (lane >> 3);
      const unsigned short* src;
      if (layer == 0)
        src = (k0 < DD) ? (Xbf + (size_t)row * TD + p * DD + k0 + (lane & 7) * 8)
                        : (hp1 + (size_t)row * HH + (k0 - DD) + (lane & 7) * 8);
      else
        src = (k0 < HH) ? (hp1 + (size_t)row * HH + k0 + (lane & 7) * 8)
                        : (hp2 + (size_t)row * HH + (k0 - HH) + (lane & 7) * 8);
      GLOAD_LDS16(src, base + ml * 64);
    }
  };

  // persistent cell state (rows m0+r, units u0+ug*8 .. +8)
  int r = tid >> 2, ug = tid & 3;
  int rg = m0 + r;
  float creg[8];
  #pragma unroll
  for (int k = 0; k < 8; ++k) creg[k] = 0.f;
  const float* bp = (layer ? b2p : b1p) + (size_t)(u0 + ug * 8) * 4;
  floatx4 bpr[8];
  #pragma unroll
  for (int k = 0; k < 8; ++k) bpr[k] = *(const floatx4*)&bp[k * 4];

  // pre-loop prefetch: B never depends on h; layer0's first A chunk is pure x
  stageB(0, 0);
  if (layer == 0) stageA(0, 0, 0);

  for (int p = 0; p <= TT; ++p) {
    bool active = layer == 0 ? (p < TT) : (p >= 1);
    if (active) {
      floatx4 acc[4][2];
      #pragma unroll
      for (int i = 0; i < 4; ++i)
        #pragma unroll
        for (int j = 0; j < 2; ++j) acc[i][j] = (floatx4){0.f, 0.f, 0.f, 0.f};
      if (layer == 1) stageA(0, 0, p);   // h-dependent: post-barrier only
      for (int it = 0; it < niter; ++it) {
        int buf = it & 1;
        __syncthreads();   // buf ready (drains vmcnt incl. cross-barrier prefetch)
        if (it + 1 < niter) { stageA(buf ^ 1, (it + 1) << 6, p); stageB(buf ^ 1, (it + 1) << 6); }
        const unsigned short* Ab = Abuf + buf * (64 * 64);
        const unsigned short* Bb = Bbuf + buf * (128 * 64);
        #pragma unroll
        for (int ks = 0; ks < 2; ++ks) {
          int qb = ks * 4 + (lane >> 4);
          short8 af[4], bfv[2];
          #pragma unroll
          for (int mi = 0; mi < 4; ++mi) {
            int ml = mi * 16 + (lane & 15);
            af[mi] = *(const short8*)&Ab[ml * 64 + ((qb ^ (ml & 7)) << 3)];
          }
          #pragma unroll
          for (int ni = 0; ni < 2; ++ni) {
            int nl = w * 32 + ni * 16 + (lane & 15);
            bfv[ni] = *(const short8*)&Bb[nl * 64 + ((qb ^ (nl & 7)) << 3)];
          }
          #pragma unroll
          for (int mi = 0; mi < 4; ++mi)
            #pragma unroll
            for (int ni = 0; ni < 2; ++ni)
              acc[mi][ni] = __builtin_amdgcn_mfma_f32_16x16x32_bf16(af[mi], bfv[ni],
                                                                    acc[mi][ni], 0, 0, 0);
        }
      }
      // prefetch next phase into buf0 (last compute buf was 1: niter even)
      bool nact = layer == 0 ? (p + 1 < TT) : (p + 1 <= TT);
      if (nact) { stageB(0, 0); if (layer == 0) stageA(0, 0, p + 1); }
      // acc -> zt (C/D: col=lane&15, row=(lane>>4)*4+rr)
      #pragma unroll
      for (int mi = 0; mi < 4; ++mi)
        #pragma unroll
        for (int ni = 0; ni < 2; ++ni)
          #pragma unroll
          for (int rr = 0; rr < 4; ++rr) {
            int row = mi * 16 + (lane >> 4) * 4 + rr;
            int col = w * 32 + ni * 16 + (lane & 15);
            zt[row * 132 + col] = acc[mi][ni][rr];
          }
      __syncthreads();
      // cell epilogue
      unsigned short* hn = (layer ? h2bufs : h1bufs) + (size_t)((p + 1) & 1) * BBHH;
      ushort8 hv;
      #pragma unroll
      for (int k = 0; k < 8; ++k) {
        floatx4 g = *(const floatx4*)&zt[r * 132 + (ug * 8 + k) * 4];
        float i_ = g[0] + bpr[k][0];
        float j_ = g[1] + bpr[k][1];
        float f_ = g[2] + bpr[k][2] + 1.f;   // FORGET_BIAS
        float o_ = g[3] + bpr[k][3];
        float nc = creg[k] * sigm(f_) + sigm(i_) * tanh_fast(j_);
        creg[k] = nc;
        hv[k] = f2bf(tanh_fast(nc) * sigm(o_));
      }
      int q = (u0 >> 3) + ug;
      *(ushort8*)&hn[(size_t)rg * HH + ((q & ~7) << 3) + (((q ^ rg) & 7) << 3)] = hv;
    }
    // ---- group barrier (release h stores -> arrival; acquire after) ----
    __syncthreads();   // all threads' h stores drained (vmcnt0 before s_barrier)
    if (tid == 0) {
      __threadfence();
      unsigned int tgt = 64u * (unsigned)(p + 1);
      if (atomicAdd(cnt, 1u) + 1u < tgt) {
        while (__hip_atomic_load(cnt, __ATOMIC_RELAXED, __HIP_MEMORY_SCOPE_AGENT) < tgt)
          __builtin_amdgcn_s_sleep(1);
      }
      __threadfence();
    }
    __syncthreads();
  }
}

// ---------------- dense head + MSE loss (h2 swizzled) ---------------------
__global__ __launch_bounds__(64) void head_loss(const unsigned short* __restrict__ h2,
                                                const float* __restrict__ Wd,
                                                const float* __restrict__ bd,
                                                const float* __restrict__ labels,
                                                float* __restrict__ out) {
  int b = blockIdx.x;
  int l = threadIdx.x;
  float pacc[24];
  #pragma unroll
  for (int n = 0; n < 24; ++n) pacc[n] = 0.f;
  for (int k = l; k < HH; k += 64) {
    int ksw = (k & ~63) | ((((k >> 3) ^ b) & 7) << 3) | (k & 7);
    float hv = bf2f(h2[(size_t)b * HH + ksw]);
    const float* wr = Wd + (size_t)k * 24;
    #pragma unroll
    for (int n = 0; n < 24; ++n) pacc[n] += hv * wr[n];
  }
  #pragma unroll
  for (int n = 0; n < 24; ++n) {
    float v = pacc[n];
    for (int off = 32; off > 0; off >>= 1) v += __shfl_down(v, off);
    pacc[n] = v;
  }
  if (l == 0) {
    float s = 0.f;
    #pragma unroll
    for (int n = 0; n < 24; ++n) {
      float pred = pacc[n] + bd[n];
      float d = pred - labels[b * 24 + n];
      s += d * d;
    }
    atomicAdd(out, s * (1.0f / 6144.0f));
  }
}

extern "C" void kernel_launch(void* const* d_in, const int* in_sizes, int n_in,
                              void* d_out, int out_size, void* d_ws, size_t ws_size,
                              hipStream_t stream) {
  const float* features = (const float*)d_in[0];
  const float* labels   = (const float*)d_in[1];
  const float* W1 = (const float*)d_in[2];
  const float* b1 = (const float*)d_in[3];
  const float* W2 = (const float*)d_in[4];
  const float* b2 = (const float*)d_in[5];
  const float* Wd = (const float*)d_in[6];
  const float* bd = (const float*)d_in[7];

  char* ws = (char*)d_ws;
  unsigned int*   cnts = (unsigned int*)(ws + OFF_CNT);
  float*          b1p  = (float*)(ws + OFF_B1P);
  float*          b2p  = (float*)(ws + OFF_B2P);
  unsigned short* h1   = (unsigned short*)(ws + OFF_H1);
  unsigned short* h2   = (unsigned short*)(ws + OFF_H2);
  unsigned short* Xbf  = (unsigned short*)(ws + OFF_X);
  unsigned short* WT1  = (unsigned short*)(ws + OFF_W1T);
  unsigned short* WT2  = (unsigned short*)(ws + OFF_W2T);
  float* out = (float*)d_out;

  init_zero<<<528, 256, 0, stream>>>(out, (uint4*)ws, 135168L);
  feat2bf<<<5376, 256, 0, stream>>>(features, Xbf, 1376256L);
  transpose_swz<<<18 * 64, 256, 0, stream>>>(W1, WT1, 1152);
  transpose_swz<<<32 * 64, 256, 0, stream>>>(W2, WT2, 2048);
  bias_perm<<<32, 256, 0, stream>>>(b1, b2, b1p, b2p);

  void* args[] = {&Xbf, &h1, &h2, &WT1, &WT2, &b1p, &b2p, &cnts};
  hipLaunchCooperativeKernel((const void*)lstm_persist, dim3(256), dim3(256),
                             args, 0, stream);

  // final h2 is buffer (TT+1)&1 = 1
  head_loss<<<256, 64, 0, stream>>>(h2 + BBHH, Wd, bd, labels, out);
}

// Round 4
// 7397.708 us; speedup vs baseline: 1.8099x; 1.8099x over previous
//
#include <hip/hip_runtime.h>

#define TT 336
#define BB 256
#define DD 128
#define HH 1024
#define TD 43008     // T*D
#define BBHH 262144  // B*H elements

typedef __attribute__((ext_vector_type(8))) short short8;
typedef __attribute__((ext_vector_type(8))) unsigned short ushort8;
typedef __attribute__((ext_vector_type(4))) unsigned short ushort4v;
typedef __attribute__((ext_vector_type(4))) float floatx4;

// ---- workspace layout (bytes) ----
#define OFF_C1  0u            // 256*1024 f32 = 1 MB
#define OFF_C2  1048576u      // 1 MB
#define OFF_H1  2097152u      // 2 bufs x 512 KB bf16 (swizzled)
#define OFF_H2  3145728u      // 2 bufs x 512 KB
#define OFF_B1P 4194304u      // 4096 f32 permuted bias
#define OFF_B2P 4210688u
#define OFF_X   4227072u      // 256*336*128 bf16 swizzled = 22020096
#define OFF_W1T 26247168u     // 4096*1152 bf16 = 9437184
#define OFF_W2T 35684352u     // 4096*2048 bf16 = 16777216
// end = 52461568

static __device__ __forceinline__ unsigned short f2bf(float f) {
  unsigned int x = __float_as_uint(f);
  x += 0x7fffu + ((x >> 16) & 1u);   // RNE
  return (unsigned short)(x >> 16);
}
static __device__ __forceinline__ float bf2f(unsigned short u) {
  return __uint_as_float(((unsigned int)u) << 16);
}
static __device__ __forceinline__ float sigm(float x) {
  return 1.f / (1.f + __expf(-x));
}
static __device__ __forceinline__ float tanh_fast(float x) {
  float ax = fabsf(x);
  float e = __expf(-2.f * ax);
  float t = (1.f - e) / (1.f + e);
  return x < 0.f ? -t : t;
}

#define GLOAD_LDS16(gsrc, ldst)                                              \
  __builtin_amdgcn_global_load_lds(                                          \
      (const __attribute__((address_space(1))) void*)(gsrc),                 \
      (__attribute__((address_space(3))) void*)(ldst), 16, 0, 0)

// -------- init: zero c1,c2,h1x2,h2x2 (4 MB) + d_out -----------------------
__global__ __launch_bounds__(256) void init_zero(float* out, uint4* span, long n16) {
  long i = (long)blockIdx.x * 256 + threadIdx.x;
  if (i < n16) span[i] = make_uint4(0u, 0u, 0u, 0u);
  if (i == 0) out[0] = 0.f;
}

// ------- features fp32 -> bf16, quad-swizzled by batch row ----------------
__global__ __launch_bounds__(256) void feat2bf(const float* __restrict__ in,
                                               unsigned short* __restrict__ out, long nq) {
  long Q = (long)blockIdx.x * 256 + threadIdx.x;
  if (Q >= nq) return;
  int b = (int)(Q / 5376);
  long outQ = (Q & ~7L) | ((Q ^ (long)b) & 7);
  const floatx4* pp = (const floatx4*)(in + Q * 8);
  floatx4 a = pp[0], c = pp[1];
  ushort8 v;
  #pragma unroll
  for (int q = 0; q < 4; ++q) { v[q] = f2bf(a[q]); v[4 + q] = f2bf(c[q]); }
  *(ushort8*)(out + outQ * 8) = v;
}

// ---- transpose W (K x 4096 f32) -> WT' (4096 x K bf16) -------------------
// gate-interleaved rows: n' = (n&1023)*4 + (n>>10); quad-XOR swizzle keyed n'
__global__ __launch_bounds__(256) void transpose_swz(const float* __restrict__ W,
                                                     unsigned short* __restrict__ out, int K) {
  __shared__ unsigned short tile[64 * 65];
  int tid = threadIdx.x;
  int ktiles = K >> 6;
  int kt = blockIdx.x % ktiles;
  int nt = blockIdx.x / ktiles;
  #pragma unroll
  for (int i = 0; i < 16; ++i) {
    int lin = i * 256 + tid;
    int lk = lin >> 6, nn = lin & 63;
    tile[lk * 65 + nn] = f2bf(W[(size_t)(kt * 64 + lk) * 4096 + nt * 64 + nn]);
  }
  __syncthreads();
  #pragma unroll
  for (int it = 0; it < 2; ++it) {
    int idx = it * 256 + tid;
    int nl = idx >> 3, ql = idx & 7;
    int norig = nt * 64 + nl;
    int np = ((norig & 1023) << 2) | (norig >> 10);
    ushort8 v;
    #pragma unroll
    for (int j = 0; j < 8; ++j) v[j] = tile[(ql * 8 + j) * 65 + nl];
    size_t off = (size_t)np * K + (size_t)((kt * 8 + (ql ^ (np & 7))) << 3);
    *(ushort8*)(out + off) = v;
  }
}

// ---- permute biases: bp[u*4+g] = b[g*1024+u] -----------------------------
__global__ __launch_bounds__(256) void bias_perm(const float* __restrict__ b1,
                                                 const float* __restrict__ b2,
                                                 float* __restrict__ b1p,
                                                 float* __restrict__ b2p) {
  int idx = blockIdx.x * 256 + threadIdx.x;
  const float* src = (idx < 4096) ? b1 : b2;
  float* dst = (idx < 4096) ? b1p : b2p;
  int n = idx & 4095;
  dst[n] = src[(n & 3) * 1024 + (n >> 2)];
}

// ---------------- fused phase: GEMM (k-split x2) + LSTM cell --------------
// 256 blocks x 512 thr (8 waves = 2/SIMD). layer=bid>>7. Tile 64 m x 128 WT'
// rows; K split in half across two 4-wave groups (own double-buffered LDS
// pipelines, lock-step via block barrier); partials reduced through zt.
__global__ __launch_bounds__(512, 2) void gemm_cell(
    const unsigned short* __restrict__ Xbf,
    unsigned short* __restrict__ h1bufs, unsigned short* __restrict__ h2bufs,
    const unsigned short* __restrict__ WT1, const unsigned short* __restrict__ WT2,
    const float* __restrict__ b1p, const float* __restrict__ b2p,
    float* __restrict__ c1, float* __restrict__ c2,
    int p, int do1, int do2) {
  __shared__ __align__(16) unsigned short Abuf[2 * 2 * 64 * 64];   // [grp][buf] 32 KB
  __shared__ __align__(16) unsigned short Bbuf[2 * 2 * 128 * 64];  // [grp][buf] 64 KB
  __shared__ __align__(16) float zt[64 * 136];                     // 34 KB (stride 136)

  int bid = blockIdx.x;
  int layer = bid >> 7;
  if (layer == 0 ? !do1 : !do2) return;
  int lid = bid & 127;
  // co-locate the 4 m-blocks of one n-tile on one XCD (bid mod 8 equal)
  int ntile = (lid & 7) | (((lid >> 5) & 3) << 3);
  int mtile = (lid >> 3) & 3;
  int m0 = mtile * 64;
  int n0 = ntile * 128;
  int u0 = ntile * 32;

  const unsigned short* hp1 = h1bufs + (size_t)(p & 1) * BBHH;
  const unsigned short* hp2 = h2bufs + (size_t)(p & 1) * BBHH;
  unsigned short* hn = (layer ? h2bufs : h1bufs) + (size_t)((p + 1) & 1) * BBHH;
  const unsigned short* Bw = layer ? WT2 : WT1;
  const int K = layer ? 2048 : 1152;
  const int KH = K >> 1;       // per-group K
  const int niter = KH >> 6;   // 16 (L1) or 9 (L0)

  int tid = threadIdx.x;
  int g = tid >> 8;            // k-half group
  int w = (tid >> 6) & 3;      // wave within group
  int lane = tid & 63;
  int kgbase = g * KH;

  auto stageB = [&](int buf, int k0) {
    unsigned short* base = Bbuf + (g * 2 + buf) * (128 * 64);
    #pragma unroll
    for (int c = 0; c < 4; ++c) {
      int nl = w * 32 + c * 8;
      const unsigned short* src =
          Bw + (size_t)(n0 + nl + (lane >> 3)) * K + kgbase + k0 + (lane & 7) * 8;
      GLOAD_LDS16(src, base + nl * 64);
    }
  };
  auto stageA = [&](int buf, int k0) {
    unsigned short* base = Abuf + (g * 2 + buf) * (64 * 64);
    int kk = kgbase + k0;
    #pragma unroll
    for (int c = 0; c < 2; ++c) {
      int ml = w * 16 + c * 8;
      int row = m0 + ml + (lane >> 3);
      const unsigned short* src;
      if (layer == 0)
        src = (kk < DD) ? (Xbf + (size_t)row * TD + p * DD + kk + (lane & 7) * 8)
                        : (hp1 + (size_t)row * HH + (kk - DD) + (lane & 7) * 8);
      else
        src = (kk < HH) ? (hp1 + (size_t)row * HH + kk + (lane & 7) * 8)
                        : (hp2 + (size_t)row * HH + (kk - HH) + (lane & 7) * 8);
      GLOAD_LDS16(src, base + ml * 64);
    }
  };

  stageA(0, 0); stageB(0, 0);

  floatx4 acc[4][2];
  #pragma unroll
  for (int i = 0; i < 4; ++i)
    #pragma unroll
    for (int j = 0; j < 2; ++j) acc[i][j] = (floatx4){0.f, 0.f, 0.f, 0.f};

  for (int it = 0; it < niter; ++it) {
    int buf = it & 1;
    __syncthreads();   // buf staged (barrier drains vmcnt)
    if (it + 1 < niter) { stageA(buf ^ 1, (it + 1) << 6); stageB(buf ^ 1, (it + 1) << 6); }
    const unsigned short* Ab = Abuf + (g * 2 + buf) * (64 * 64);
    const unsigned short* Bb = Bbuf + (g * 2 + buf) * (128 * 64);
    #pragma unroll
    for (int ks = 0; ks < 2; ++ks) {
      int qb = ks * 4 + (lane >> 4);
      short8 af[4], bfv[2];
      #pragma unroll
      for (int mi = 0; mi < 4; ++mi) {
        int ml = mi * 16 + (lane & 15);
        af[mi] = *(const short8*)&Ab[ml * 64 + ((qb ^ (ml & 7)) << 3)];
      }
      #pragma unroll
      for (int ni = 0; ni < 2; ++ni) {
        int nl = w * 32 + ni * 16 + (lane & 15);
        bfv[ni] = *(const short8*)&Bb[nl * 64 + ((qb ^ (nl & 7)) << 3)];
      }
      #pragma unroll
      for (int mi = 0; mi < 4; ++mi)
        #pragma unroll
        for (int ni = 0; ni < 2; ++ni)
          acc[mi][ni] = __builtin_amdgcn_mfma_f32_16x16x32_bf16(af[mi], bfv[ni],
                                                                acc[mi][ni], 0, 0, 0);
    }
  }
  __syncthreads();

  // reduce partials through zt (C/D: col=lane&15, row=(lane>>4)*4+rr)
  if (g == 0) {
    #pragma unroll
    for (int mi = 0; mi < 4; ++mi)
      #pragma unroll
      for (int ni = 0; ni < 2; ++ni)
        #pragma unroll
        for (int rr = 0; rr < 4; ++rr) {
          int row = mi * 16 + (lane >> 4) * 4 + rr;
          int col = w * 32 + ni * 16 + (lane & 15);
          zt[row * 136 + col] = acc[mi][ni][rr];
        }
  }
  __syncthreads();
  if (g == 1) {
    #pragma unroll
    for (int mi = 0; mi < 4; ++mi)
      #pragma unroll
      for (int ni = 0; ni < 2; ++ni)
        #pragma unroll
        for (int rr = 0; rr < 4; ++rr) {
          int row = mi * 16 + (lane >> 4) * 4 + rr;
          int col = w * 32 + ni * 16 + (lane & 15);
          zt[row * 136 + col] += acc[mi][ni][rr];
        }
  }
  __syncthreads();

  // cell: 512 thr, each 4 units. r=tid>>3 (row), ug=tid&7 (4-unit group)
  {
    int r = tid >> 3, ug = tid & 7;
    int rg = m0 + r;
    float* cp = (layer ? c2 : c1) + (size_t)rg * HH + u0 + ug * 4;
    const float* bp = (layer ? b2p : b1p) + (size_t)(u0 + ug * 4) * 4;
    floatx4 cold = *(const floatx4*)cp;
    floatx4 cn;
    ushort4v hv;
    #pragma unroll
    for (int k = 0; k < 4; ++k) {
      floatx4 gt = *(const floatx4*)&zt[r * 136 + (ug * 4 + k) * 4];
      floatx4 bb = *(const floatx4*)&bp[k * 4];
      float i_ = gt[0] + bb[0];
      float j_ = gt[1] + bb[1];
      float f_ = gt[2] + bb[2] + 1.f;   // FORGET_BIAS
      float o_ = gt[3] + bb[3];
      float nc = cold[k] * sigm(f_) + sigm(i_) * tanh_fast(j_);
      cn[k] = nc;
      hv[k] = f2bf(tanh_fast(nc) * sigm(o_));
    }
    *(floatx4*)cp = cn;
    int q = (u0 >> 3) + (ug >> 1);   // h quad; swizzle keyed by batch row
    *(ushort4v*)&hn[(size_t)rg * HH + (((q & ~7) | ((q ^ rg) & 7)) << 3) + (ug & 1) * 4] = hv;
  }
}

// ---------------- dense head + MSE loss (h2 swizzled) ---------------------
__global__ __launch_bounds__(64) void head_loss(const unsigned short* __restrict__ h2,
                                                const float* __restrict__ Wd,
                                                const float* __restrict__ bd,
                                                const float* __restrict__ labels,
                                                float* __restrict__ out) {
  int b = blockIdx.x;
  int l = threadIdx.x;
  float pacc[24];
  #pragma unroll
  for (int n = 0; n < 24; ++n) pacc[n] = 0.f;
  for (int k = l; k < HH; k += 64) {
    int ksw = (k & ~63) | ((((k >> 3) ^ b) & 7) << 3) | (k & 7);
    float hv = bf2f(h2[(size_t)b * HH + ksw]);
    const float* wr = Wd + (size_t)k * 24;
    #pragma unroll
    for (int n = 0; n < 24; ++n) pacc[n] += hv * wr[n];
  }
  #pragma unroll
  for (int n = 0; n < 24; ++n) {
    float v = pacc[n];
    for (int off = 32; off > 0; off >>= 1) v += __shfl_down(v, off);
    pacc[n] = v;
  }
  if (l == 0) {
    float s = 0.f;
    #pragma unroll
    for (int n = 0; n < 24; ++n) {
      float pred = pacc[n] + bd[n];
      float d = pred - labels[b * 24 + n];
      s += d * d;
    }
    atomicAdd(out, s * (1.0f / 6144.0f));
  }
}

extern "C" void kernel_launch(void* const* d_in, const int* in_sizes, int n_in,
                              void* d_out, int out_size, void* d_ws, size_t ws_size,
                              hipStream_t stream) {
  const float* features = (const float*)d_in[0];
  const float* labels   = (const float*)d_in[1];
  const float* W1 = (const float*)d_in[2];
  const float* b1 = (const float*)d_in[3];
  const float* W2 = (const float*)d_in[4];
  const float* b2 = (const float*)d_in[5];
  const float* Wd = (const float*)d_in[6];
  const float* bd = (const float*)d_in[7];

  char* ws = (char*)d_ws;
  float*          c1  = (float*)(ws + OFF_C1);
  float*          c2  = (float*)(ws + OFF_C2);
  unsigned short* h1  = (unsigned short*)(ws + OFF_H1);
  unsigned short* h2  = (unsigned short*)(ws + OFF_H2);
  float*          b1p = (float*)(ws + OFF_B1P);
  float*          b2p = (float*)(ws + OFF_B2P);
  unsigned short* Xbf = (unsigned short*)(ws + OFF_X);
  unsigned short* WT1 = (unsigned short*)(ws + OFF_W1T);
  unsigned short* WT2 = (unsigned short*)(ws + OFF_W2T);
  float* out = (float*)d_out;

  init_zero<<<1024, 256, 0, stream>>>(out, (uint4*)ws, 262144L);
  feat2bf<<<5376, 256, 0, stream>>>(features, Xbf, 1376256L);
  transpose_swz<<<18 * 64, 256, 0, stream>>>(W1, WT1, 1152);
  transpose_swz<<<32 * 64, 256, 0, stream>>>(W2, WT2, 2048);
  bias_perm<<<32, 256, 0, stream>>>(b1, b2, b1p, b2p);

  // phase p: layer0 computes h1(p) [p<T]; layer1 computes h2(p-1) [p>=1]
  for (int p = 0; p <= TT; ++p) {
    gemm_cell<<<256, 512, 0, stream>>>(Xbf, h1, h2, WT1, WT2, b1p, b2p, c1, c2,
                                       p, p < TT ? 1 : 0, p >= 1 ? 1 : 0);
  }
  // final h2 is buffer (TT+1)&1 = 1
  head_loss<<<256, 64, 0, stream>>>(h2 + BBHH, Wd, bd, labels, out);
}

// Round 5
// 6539.548 us; speedup vs baseline: 2.0474x; 1.1312x over previous
//
#include <hip/hip_runtime.h>

#define TT 336
#define BB 256
#define DD 128
#define HH 1024
#define TD 43008     // T*D
#define BBHH 262144  // B*H elements

// B-pack geometry (ushort units)
#define SSU0 20480u     // layer0 wave stream: 10 ks * 4 ni * 512
#define SSU1 32768u     // layer1 wave stream: 16 ks * 4 ni * 512
#define LBU1 5242880u   // layer1 base = 32 ntiles * 8 slots * SSU0

typedef __attribute__((ext_vector_type(8))) short short8;
typedef __attribute__((ext_vector_type(8))) unsigned short ushort8;
typedef __attribute__((ext_vector_type(4))) unsigned short ushort4v;
typedef __attribute__((ext_vector_type(4))) float floatx4;

// ---- workspace layout (bytes) ----
#define OFF_ZPAD 0u          // 4 KB zero pad (K-padding source)
#define OFF_C1   4096u       // 1 MB
#define OFF_C2   1052672u    // 1 MB
#define OFF_H1   2101248u    // 2 bufs x 512 KB bf16 (swizzled)
#define OFF_H2   3149824u
#define OFF_B1P  4198400u    // 16 KB permuted bias
#define OFF_B2P  4214784u
#define OFF_X    4231168u    // 22,020,096
#define OFF_BP   26251264u   // fragment-linear weight pack, 27,262,976
// end = 53,514,240

static __device__ __forceinline__ unsigned short f2bf(float f) {
  unsigned int x = __float_as_uint(f);
  x += 0x7fffu + ((x >> 16) & 1u);   // RNE
  return (unsigned short)(x >> 16);
}
static __device__ __forceinline__ float bf2f(unsigned short u) {
  return __uint_as_float(((unsigned int)u) << 16);
}
static __device__ __forceinline__ float sigm(float x) {
  return 1.f / (1.f + __expf(-x));
}
static __device__ __forceinline__ float tanh_fast(float x) {
  float ax = fabsf(x);
  float e = __expf(-2.f * ax);
  float t = (1.f - e) / (1.f + e);
  return x < 0.f ? -t : t;
}

#define GLOAD_LDS16(gsrc, ldst)                                              \
  __builtin_amdgcn_global_load_lds(                                          \
      (const __attribute__((address_space(1))) void*)(gsrc),                 \
      (__attribute__((address_space(3))) void*)(ldst), 16, 0, 0)

// -------- init: zero zpad,c1,c2,h bufs [0, OFF_B1P) + d_out ---------------
__global__ __launch_bounds__(256) void init_zero(float* out, uint4* span, long n16) {
  long i = (long)blockIdx.x * 256 + threadIdx.x;
  if (i < n16) span[i] = make_uint4(0u, 0u, 0u, 0u);
  if (i == 0) out[0] = 0.f;
}

// ------- features fp32 -> bf16, quad-swizzled by batch row ----------------
__global__ __launch_bounds__(256) void feat2bf(const float* __restrict__ in,
                                               unsigned short* __restrict__ out, long nq) {
  long Q = (long)blockIdx.x * 256 + threadIdx.x;
  if (Q >= nq) return;
  int b = (int)(Q / 5376);
  long outQ = (Q & ~7L) | ((Q ^ (long)b) & 7);
  const floatx4* pp = (const floatx4*)(in + Q * 8);
  floatx4 a = pp[0], c = pp[1];
  ushort8 v;
  #pragma unroll
  for (int q = 0; q < 4; ++q) { v[q] = f2bf(a[q]); v[4 + q] = f2bf(c[q]); }
  *(ushort8*)(out + outQ * 8) = v;
}

// ---- pack W (K x 4096 f32) into fragment-linear bf16 ---------------------
// Frag lane l of (ntile,g,wn,ksg,ni) = WT'[ntile*128+wn*64+ni*16+(l&15)]
//   [g*KG + ksg*32 + (l>>4)*8 + j], where WT' row n' maps to W col
//   norig = (n'&3)*1024 + (n'>>2) (gate-interleave). Layer0 K padded to 1280.
__global__ __launch_bounds__(256) void bpack(const float* __restrict__ W1,
                                             const float* __restrict__ W2,
                                             unsigned short* __restrict__ out) {
  __shared__ unsigned short tile[64][72];
  int bid = blockIdx.x, t = threadIdx.x;
  int L, tk, tn;
  if (bid < 1280) { L = 0; tk = bid % 20; tn = bid / 20; }
  else            { L = 1; tk = (bid - 1280) % 32; tn = (bid - 1280) / 32; }
  const float* W = L ? W2 : W1;
  int KG = L ? 512 : 320;
  int k0 = tk * 64, n0p = tn * 64;
  int g = k0 / KG;
  int ksg0 = (k0 - g * KG) >> 5;
  int ntile = n0p >> 7, wn = (n0p >> 6) & 1;
  unsigned int SSu = L ? SSU1 : SSU0;
  unsigned int base = (L ? LBU1 : 0u) + ntile * 8u * SSu + (g * 2 + wn) * SSu;

  #pragma unroll
  for (int i = 0; i < 16; ++i) {
    int idx = i * 256 + t;
    int kk = idx >> 6, nn = idx & 63;
    int np = n0p + nn;
    int norig = ((np & 3) << 10) + (np >> 2);
    float v = 0.f;
    if (!(L == 0 && k0 + kk >= 1152)) v = W[(size_t)(k0 + kk) * 4096 + norig];
    tile[kk][nn] = f2bf(v);
  }
  __syncthreads();
  int t64 = t & 63;
  #pragma unroll
  for (int pass = 0; pass < 2; ++pass) {
    int f = (t >> 6) + pass * 4;
    int ksl = f >> 2, ni = f & 3;
    ushort8 v;
    #pragma unroll
    for (int j = 0; j < 8; ++j)
      v[j] = tile[ksl * 32 + ((t64 >> 4) << 3) + j][ni * 16 + (t64 & 15)];
    *(ushort8*)(out + base + (unsigned)((ksg0 + ksl) * 4 + ni) * 512u + t64 * 8) = v;
  }
}

// ---- permute biases: bp[u*4+g] = b[g*1024+u] -----------------------------
__global__ __launch_bounds__(256) void bias_perm(const float* __restrict__ b1,
                                                 const float* __restrict__ b2,
                                                 float* __restrict__ b1p,
                                                 float* __restrict__ b2p) {
  int idx = blockIdx.x * 256 + threadIdx.x;
  const float* src = (idx < 4096) ? b1 : b2;
  float* dst = (idx < 4096) ? b1p : b2p;
  int n = idx & 4095;
  dst[n] = src[(n & 3) * 1024 + (n >> 2)];
}

// ---------------- fused phase: GEMM (ksplit x4, B-from-registers) + cell --
// 256 blocks x 512 thr. layer=bid>>7. Block tile 64m x 128n'.
// 4 k-groups x 2 waves; wave tile 64m x 64n. A via LDS (swizzled), B frags
// streamed global->VGPR from fragment-linear pack. 2-buffer zt reduction.
__global__ __launch_bounds__(512, 2) void gemm_cell(
    const unsigned short* __restrict__ Xbf,
    unsigned short* __restrict__ h1bufs, unsigned short* __restrict__ h2bufs,
    const unsigned short* __restrict__ Bpack,
    const float* __restrict__ b1p, const float* __restrict__ b2p,
    float* __restrict__ c1, float* __restrict__ c2,
    const unsigned short* __restrict__ zpad,
    int p, int do1, int do2) {
  __shared__ __align__(16) unsigned short Abuf[4][2][64 * 64];  // 64 KB
  __shared__ __align__(16) float zt0[64 * 132];                 // 33.8 KB
  __shared__ __align__(16) float zt1[64 * 132];                 // 33.8 KB

  int bid = blockIdx.x;
  int layer = bid >> 7;
  if (layer == 0 ? !do1 : !do2) return;
  int lid = bid & 127;
  // co-locate the 4 m-blocks of one n-tile on one XCD (bid mod 8 equal)
  int ntile = (lid & 7) | (((lid >> 5) & 3) << 3);
  int mtile = (lid >> 3) & 3;
  int m0 = mtile * 64;
  int u0 = ntile * 32;

  const unsigned short* hp1 = h1bufs + (size_t)(p & 1) * BBHH;
  const unsigned short* hp2 = h2bufs + (size_t)(p & 1) * BBHH;
  const int KG = layer ? 512 : 320;
  const int NIT = KG >> 6;   // 8 or 5

  int tid = threadIdx.x;
  int g = tid >> 7;           // k-group 0..3
  int wn = (tid >> 6) & 1;    // wave-in-group (n half)
  int lane = tid & 63;
  int kgbase = g * KG;

  unsigned int SSu = layer ? SSU1 : SSU0;
  const unsigned short* bwave =
      Bpack + (layer ? LBU1 : 0u) + ntile * 8u * SSu + (unsigned)(g * 2 + wn) * SSu;

  auto stageA = [&](int buf, int it) {
    int kb = kgbase + (it << 6);
    unsigned short* dst0 = &Abuf[g][buf][0];
    #pragma unroll
    for (int c = 0; c < 4; ++c) {
      int rowbase = c * 16 + wn * 8;          // wave-uniform
      int rg = m0 + rowbase + (lane >> 3);
      int kq = lane & 7;
      const unsigned short* src;
      if (layer == 0) {
        if (kb < DD)        src = Xbf + (size_t)rg * TD + p * DD + kb + kq * 8;
        else if (kb < 1152) src = hp1 + (size_t)rg * HH + (kb - DD) + kq * 8;
        else                src = zpad + lane * 8;   // zero K-pad
      } else {
        if (kb < HH) src = hp1 + (size_t)rg * HH + kb + kq * 8;
        else         src = hp2 + (size_t)rg * HH + (kb - HH) + kq * 8;
      }
      GLOAD_LDS16(src, dst0 + rowbase * 64);
    }
  };
  auto loadB = [&](ushort8 (&dst)[2][4], int it) {
    #pragma unroll
    for (int ksl = 0; ksl < 2; ++ksl)
      #pragma unroll
      for (int ni = 0; ni < 4; ++ni)
        dst[ksl][ni] =
            *(const ushort8*)(bwave + (unsigned)((it * 2 + ksl) * 4 + ni) * 512u + lane * 8);
  };

  floatx4 acc[4][4];
  #pragma unroll
  for (int i = 0; i < 4; ++i)
    #pragma unroll
    for (int j = 0; j < 4; ++j) acc[i][j] = (floatx4){0.f, 0.f, 0.f, 0.f};

  ushort8 bc[2][4], bn[2][4];
  stageA(0, 0);
  loadB(bc, 0);

  for (int it = 0; it < NIT; ++it) {
    int buf = it & 1;
    __syncthreads();   // group's A chunk ready (barrier drains vmcnt)
    if (it + 1 < NIT) { stageA(buf ^ 1, it + 1); loadB(bn, it + 1); }
    const unsigned short* Ab = &Abuf[g][buf][0];
    #pragma unroll
    for (int ksl = 0; ksl < 2; ++ksl) {
      int qb = ksl * 4 + (lane >> 4);
      short8 af[4];
      #pragma unroll
      for (int mi = 0; mi < 4; ++mi) {
        int ml = mi * 16 + (lane & 15);
        af[mi] = *(const short8*)&Ab[ml * 64 + ((qb ^ (ml & 7)) << 3)];
      }
      #pragma unroll
      for (int mi = 0; mi < 4; ++mi)
        #pragma unroll
        for (int ni = 0; ni < 4; ++ni)
          acc[mi][ni] = __builtin_amdgcn_mfma_f32_16x16x32_bf16(
              af[mi], (short8)bc[ksl][ni], acc[mi][ni], 0, 0, 0);
    }
    #pragma unroll
    for (int ksl = 0; ksl < 2; ++ksl)
      #pragma unroll
      for (int ni = 0; ni < 4; ++ni) bc[ksl][ni] = bn[ksl][ni];
  }

  // ---- 4-partial reduction through zt0 (g0+g2) and zt1 (g1+g3) ----
  float* ztw = (g & 1) ? zt1 : zt0;
  if (g < 2) {
    #pragma unroll
    for (int mi = 0; mi < 4; ++mi)
      #pragma unroll
      for (int ni = 0; ni < 4; ++ni)
        #pragma unroll
        for (int rr = 0; rr < 4; ++rr) {
          int row = mi * 16 + (lane >> 4) * 4 + rr;
          int col = wn * 64 + ni * 16 + (lane & 15);
          ztw[row * 132 + col] = acc[mi][ni][rr];
        }
  }
  __syncthreads();
  if (g >= 2) {
    #pragma unroll
    for (int mi = 0; mi < 4; ++mi)
      #pragma unroll
      for (int ni = 0; ni < 4; ++ni)
        #pragma unroll
        for (int rr = 0; rr < 4; ++rr) {
          int row = mi * 16 + (lane >> 4) * 4 + rr;
          int col = wn * 64 + ni * 16 + (lane & 15);
          ztw[row * 132 + col] += acc[mi][ni][rr];
        }
  }
  __syncthreads();

  // ---- cell: 512 thr, each 4 units. r=tid>>3, ug=tid&7 ----
  {
    unsigned short* hn = (layer ? h2bufs : h1bufs) + (size_t)((p + 1) & 1) * BBHH;
    int r = tid >> 3, ug = tid & 7;
    int rg = m0 + r;
    float* cp = (layer ? c2 : c1) + (size_t)rg * HH + u0 + ug * 4;
    const float* bp = (layer ? b2p : b1p) + (size_t)(u0 + ug * 4) * 4;
    floatx4 cold = *(const floatx4*)cp;
    floatx4 cn;
    ushort4v hv;
    #pragma unroll
    for (int k = 0; k < 4; ++k) {
      int cbase = r * 132 + (ug * 4 + k) * 4;
      floatx4 gt0 = *(const floatx4*)&zt0[cbase];
      floatx4 gt1 = *(const floatx4*)&zt1[cbase];
      floatx4 bb = *(const floatx4*)&bp[k * 4];
      float i_ = gt0[0] + gt1[0] + bb[0];
      float j_ = gt0[1] + gt1[1] + bb[1];
      float f_ = gt0[2] + gt1[2] + bb[2] + 1.f;   // FORGET_BIAS
      float o_ = gt0[3] + gt1[3] + bb[3];
      float nc = cold[k] * sigm(f_) + sigm(i_) * tanh_fast(j_);
      cn[k] = nc;
      hv[k] = f2bf(tanh_fast(nc) * sigm(o_));
    }
    *(floatx4*)cp = cn;
    int q = (u0 >> 3) + (ug >> 1);   // h quad; swizzle keyed by batch row
    *(ushort4v*)&hn[(size_t)rg * HH + (((q & ~7) | ((q ^ rg) & 7)) << 3) + (ug & 1) * 4] = hv;
  }
}

// ---------------- dense head + MSE loss (h2 swizzled) ---------------------
__global__ __launch_bounds__(64) void head_loss(const unsigned short* __restrict__ h2,
                                                const float* __restrict__ Wd,
                                                const float* __restrict__ bd,
                                                const float* __restrict__ labels,
                                                float* __restrict__ out) {
  int b = blockIdx.x;
  int l = threadIdx.x;
  float pacc[24];
  #pragma unroll
  for (int n = 0; n < 24; ++n) pacc[n] = 0.f;
  for (int k = l; k < HH; k += 64) {
    int ksw = (k & ~63) | ((((k >> 3) ^ b) & 7) << 3) | (k & 7);
    float hv = bf2f(h2[(size_t)b * HH + ksw]);
    const float* wr = Wd + (size_t)k * 24;
    #pragma unroll
    for (int n = 0; n < 24; ++n) pacc[n] += hv * wr[n];
  }
  #pragma unroll
  for (int n = 0; n < 24; ++n) {
    float v = pacc[n];
    for (int off = 32; off > 0; off >>= 1) v += __shfl_down(v, off);
    pacc[n] = v;
  }
  if (l == 0) {
    float s = 0.f;
    #pragma unroll
    for (int n = 0; n < 24; ++n) {
      float pred = pacc[n] + bd[n];
      float d = pred - labels[b * 24 + n];
      s += d * d;
    }
    atomicAdd(out, s * (1.0f / 6144.0f));
  }
}

extern "C" void kernel_launch(void* const* d_in, const int* in_sizes, int n_in,
                              void* d_out, int out_size, void* d_ws, size_t ws_size,
                              hipStream_t stream) {
  const float* features = (const float*)d_in[0];
  const float* labels   = (const float*)d_in[1];
  const float* W1 = (const float*)d_in[2];
  const float* b1 = (const float*)d_in[3];
  const float* W2 = (const float*)d_in[4];
  const float* b2 = (const float*)d_in[5];
  const float* Wd = (const float*)d_in[6];
  const float* bd = (const float*)d_in[7];

  char* ws = (char*)d_ws;
  unsigned short* zpad = (unsigned short*)(ws + OFF_ZPAD);
  float*          c1   = (float*)(ws + OFF_C1);
  float*          c2   = (float*)(ws + OFF_C2);
  unsigned short* h1   = (unsigned short*)(ws + OFF_H1);
  unsigned short* h2   = (unsigned short*)(ws + OFF_H2);
  float*          b1p  = (float*)(ws + OFF_B1P);
  float*          b2p  = (float*)(ws + OFF_B2P);
  unsigned short* Xbf  = (unsigned short*)(ws + OFF_X);
  unsigned short* BP   = (unsigned short*)(ws + OFF_BP);
  float* out = (float*)d_out;

  init_zero<<<1026, 256, 0, stream>>>(out, (uint4*)ws, 262400L);
  feat2bf<<<5376, 256, 0, stream>>>(features, Xbf, 1376256L);
  bpack<<<3328, 256, 0, stream>>>(W1, W2, BP);
  bias_perm<<<32, 256, 0, stream>>>(b1, b2, b1p, b2p);

  // phase p: layer0 computes h1(p) [p<T]; layer1 computes h2(p-1) [p>=1]
  for (int p = 0; p <= TT; ++p) {
    gemm_cell<<<256, 512, 0, stream>>>(Xbf, h1, h2, BP, b1p, b2p, c1, c2, zpad,
                                       p, p < TT ? 1 : 0, p >= 1 ? 1 : 0);
  }
  // final h2 is buffer (TT+1)&1 = 1
  head_loss<<<256, 64, 0, stream>>>(h2 + BBHH, Wd, bd, labels, out);
}